// Round 1
// baseline (4274.652 us; speedup 1.0000x reference)
//
#include <hip/hip_runtime.h>
#include <math.h>

#define L_TOK 69120
#define C_DIM 384
#define C3 1152
#define C4 1536
#define N_TOK 120
#define N_WIN 576
#define N_HEAD 12
#define D_HEAD 32
#define BIAS_ROWS 2736
#define WH 6912
#define CHUNK 8640
#define NCHUNK 8

__device__ __forceinline__ unsigned short f2bf(float f) {
    union { float f; unsigned int u; } c; c.f = f;
    unsigned int u = c.u;
    return (unsigned short)((u + 0x7fffu + ((u >> 16) & 1u)) >> 16);
}
__device__ __forceinline__ float bf2f(unsigned short s) {
    union { unsigned int u; float f; } c; c.u = ((unsigned int)s) << 16;
    return c.f;
}

// window-order row m = w_idx*120 + n  ->  global token index
__device__ __forceinline__ int win_to_global(int m) {
    int w_idx = m / N_TOK;
    int n = m - w_idx * N_TOK;
    int zw = w_idx / 144;            // 144 = 8*18 (hw,ww tiles)
    int rem = w_idx - zw * 144;
    int hw = rem / 18;
    int ww = rem - hw * 18;
    int zl = n / 60;
    int r2 = n - zl * 60;
    int hl = r2 / 10;
    int wl = r2 - hl * 10;
    int z = zw * 2 + zl;
    int hh = hw * 6 + hl;
    int wc = ww * 10 + wl;
    return (z * 48 + hh) * 180 + wc;
}

// ---------------- K1: qkv = window_partition(x) @ wqkv + bqkv ----------------
// out: q,k,v bf16 in (win, head, n, d) layout; q pre-scaled by 1/sqrt(32)
__global__ __launch_bounds__(256) void k_qkv(
    const float* __restrict__ x, const float* __restrict__ wqkv,
    const float* __restrict__ bqkv, unsigned short* __restrict__ q,
    unsigned short* __restrict__ k, unsigned short* __restrict__ v)
{
    __shared__ float As[16][68];
    __shared__ float Bs[16][64];
    const int tx = threadIdx.x, ty = threadIdx.y;
    const int tid = ty * 16 + tx;
    const int m0 = blockIdx.y * 64;
    const int n0 = blockIdx.x * 64;
    const int ra = tid >> 2;
    const int ka = (tid & 3) << 2;
    const int g = win_to_global(m0 + ra);
    const float* arow = x + (size_t)g * C_DIM + ka;
    const int kb = tid >> 4;
    const int nb = (tid & 15) << 2;
    const float* bp = wqkv + (size_t)kb * C3 + n0 + nb;

    float acc[4][4];
#pragma unroll
    for (int i = 0; i < 4; ++i)
#pragma unroll
        for (int j = 0; j < 4; ++j) acc[i][j] = 0.f;

    for (int kk = 0; kk < C_DIM; kk += 16) {
        float4 a4 = *(const float4*)(arow + kk);
        As[ka + 0][ra] = a4.x;
        As[ka + 1][ra] = a4.y;
        As[ka + 2][ra] = a4.z;
        As[ka + 3][ra] = a4.w;
        *(float4*)&Bs[kb][nb] = *(const float4*)(bp + (size_t)kk * C3);
        __syncthreads();
#pragma unroll
        for (int kq = 0; kq < 16; ++kq) {
            float4 av = *(const float4*)&As[kq][ty << 2];
            float4 bv = *(const float4*)&Bs[kq][tx << 2];
            float aa[4] = {av.x, av.y, av.z, av.w};
            float bb[4] = {bv.x, bv.y, bv.z, bv.w};
#pragma unroll
            for (int i = 0; i < 4; ++i)
#pragma unroll
                for (int j = 0; j < 4; ++j) acc[i][j] += aa[i] * bb[j];
        }
        __syncthreads();
    }

    const int col0 = n0 + (tx << 2);
    const int sel = col0 / C_DIM;          // uniform per block (64 | 384)
    const int c2 = col0 - sel * C_DIM;
    const int head = c2 >> 5;
    const int dd = c2 & 31;
    unsigned short* dstbuf = (sel == 0) ? q : (sel == 1) ? k : v;
    const float scl = (sel == 0) ? 0.17677669529663687f : 1.0f;
    float b4[4] = {bqkv[col0], bqkv[col0 + 1], bqkv[col0 + 2], bqkv[col0 + 3]};
#pragma unroll
    for (int i = 0; i < 4; ++i) {
        int row = m0 + (ty << 2) + i;
        int w_idx = row / N_TOK;
        int n = row - w_idx * N_TOK;
        size_t dst = (((size_t)(w_idx * N_HEAD + head) * N_TOK + n) << 5) + dd;
        ushort4 o;
        o.x = f2bf((acc[i][0] + b4[0]) * scl);
        o.y = f2bf((acc[i][1] + b4[1]) * scl);
        o.z = f2bf((acc[i][2] + b4[2]) * scl);
        o.w = f2bf((acc[i][3] + b4[3]) * scl);
        *(ushort4*)(dstbuf + dst) = o;
    }
}

// ---------------- K2: windowed attention with earth-position bias ----------------
// one block per (window, head); online softmax; writes "weird reshape" layout:
// ao[w*120 + h*10 + n/12, (n%12)*32 + dd]
__global__ __launch_bounds__(128) void k_attn(
    const unsigned short* __restrict__ q, const unsigned short* __restrict__ k,
    const unsigned short* __restrict__ v, const float* __restrict__ btab,
    unsigned short* __restrict__ ao)
{
    const int wh = blockIdx.x;
    const int w = wh / N_HEAD;
    const int h = wh - w * N_HEAD;
    __shared__ float Ks[N_TOK][D_HEAD];
    __shared__ float Vs[N_TOK][D_HEAD];
    __shared__ float blds[BIAS_ROWS];
    const int t = threadIdx.x;
    const unsigned short* kbase = k + (size_t)wh * N_TOK * D_HEAD;
    const unsigned short* vbase = v + (size_t)wh * N_TOK * D_HEAD;
    for (int i = t; i < N_TOK * D_HEAD; i += 128) {
        Ks[i >> 5][i & 31] = bf2f(kbase[i]);
        Vs[i >> 5][i & 31] = bf2f(vbase[i]);
    }
    for (int i = t; i < BIAS_ROWS; i += 128)
        blds[i] = btab[(size_t)i * WH + wh];
    __syncthreads();

    if (t < N_TOK) {
        const int n = t;
        float qr[D_HEAD];
        const unsigned short* qrow = q + ((size_t)wh * N_TOK + n) * D_HEAD;
#pragma unroll
        for (int d = 0; d < D_HEAD; ++d) qr[d] = bf2f(qrow[d]);
        int zl = n / 60;
        int r2 = n - zl * 60;
        int hl = r2 / 10;
        int wl = r2 - hl * 10;
        const int pbase = zl * 684 + hl * 19 + wl + 9;
        float mx = -1e30f, l = 0.f;
        float o[D_HEAD];
#pragma unroll
        for (int d = 0; d < D_HEAD; ++d) o[d] = 0.f;
        int z2 = 0, h2 = 0, w2 = 0;
        for (int m = 0; m < N_TOK; ++m) {
            int pos = pbase + z2 * 1368 + h2 * 114 - w2;
            float s = blds[pos];
#pragma unroll
            for (int d = 0; d < D_HEAD; ++d) s += qr[d] * Ks[m][d];
            float mnew = fmaxf(mx, s);
            float fac = __expf(mx - mnew);
            float p = __expf(s - mnew);
            l = l * fac + p;
#pragma unroll
            for (int d = 0; d < D_HEAD; ++d) o[d] = o[d] * fac + p * Vs[m][d];
            mx = mnew;
            if (++w2 == 10) { w2 = 0; if (++h2 == 6) { h2 = 0; ++z2; } }
        }
        float inv = 1.f / l;
        int r = h * 10 + n / 12;
        int c0 = (n - (n / 12) * 12) * 32;
        unsigned short* aor = ao + ((size_t)w * N_TOK + r) * C_DIM + c0;
#pragma unroll
        for (int d = 0; d < D_HEAD; ++d) aor[d] = f2bf(o[d] * inv);
    }
}

// ---------------- K3: proj GEMM + window reverse (row permute) ----------------
__global__ __launch_bounds__(256) void k_proj(
    const unsigned short* __restrict__ ao, const float* __restrict__ wproj,
    const float* __restrict__ bproj, float* __restrict__ p)
{
    __shared__ float As[16][68];
    __shared__ float Bs[16][64];
    const int tx = threadIdx.x, ty = threadIdx.y;
    const int tid = ty * 16 + tx;
    const int m0 = blockIdx.y * 64;
    const int n0 = blockIdx.x * 64;
    const int ra = tid >> 2;
    const int ka = (tid & 3) << 2;
    const unsigned short* arow = ao + (size_t)(m0 + ra) * C_DIM + ka;
    const int kb = tid >> 4;
    const int nb = (tid & 15) << 2;
    const float* bp = wproj + (size_t)kb * C_DIM + n0 + nb;

    float acc[4][4];
#pragma unroll
    for (int i = 0; i < 4; ++i)
#pragma unroll
        for (int j = 0; j < 4; ++j) acc[i][j] = 0.f;

    for (int kk = 0; kk < C_DIM; kk += 16) {
        ushort4 a4 = *(const ushort4*)(arow + kk);
        As[ka + 0][ra] = bf2f(a4.x);
        As[ka + 1][ra] = bf2f(a4.y);
        As[ka + 2][ra] = bf2f(a4.z);
        As[ka + 3][ra] = bf2f(a4.w);
        *(float4*)&Bs[kb][nb] = *(const float4*)(bp + (size_t)kk * C_DIM);
        __syncthreads();
#pragma unroll
        for (int kq = 0; kq < 16; ++kq) {
            float4 av = *(const float4*)&As[kq][ty << 2];
            float4 bv = *(const float4*)&Bs[kq][tx << 2];
            float aa[4] = {av.x, av.y, av.z, av.w};
            float bb[4] = {bv.x, bv.y, bv.z, bv.w};
#pragma unroll
            for (int i = 0; i < 4; ++i)
#pragma unroll
                for (int j = 0; j < 4; ++j) acc[i][j] += aa[i] * bb[j];
        }
        __syncthreads();
    }

    const int col0 = n0 + (tx << 2);
    float4 bb4 = *(const float4*)(bproj + col0);
#pragma unroll
    for (int i = 0; i < 4; ++i) {
        int row = m0 + (ty << 2) + i;
        int g = win_to_global(row);
        float4 o;
        o.x = acc[i][0] + bb4.x;
        o.y = acc[i][1] + bb4.y;
        o.z = acc[i][2] + bb4.z;
        o.w = acc[i][3] + bb4.w;
        *(float4*)(p + (size_t)g * C_DIM + col0) = o;
    }
}

// ---------------- K5: mlp1 GEMM + exact GELU ----------------
__global__ __launch_bounds__(256) void k_mlp1(
    const float* __restrict__ x1, const float* __restrict__ wm1,
    const float* __restrict__ bm1, unsigned short* __restrict__ hbuf)
{
    __shared__ float As[16][68];
    __shared__ float Bs[16][64];
    const int tx = threadIdx.x, ty = threadIdx.y;
    const int tid = ty * 16 + tx;
    const int m0 = blockIdx.y * 64;
    const int n0 = blockIdx.x * 64;
    const int ra = tid >> 2;
    const int ka = (tid & 3) << 2;
    const float* arow = x1 + (size_t)(m0 + ra) * C_DIM + ka;
    const int kb = tid >> 4;
    const int nb = (tid & 15) << 2;
    const float* bp = wm1 + (size_t)kb * C4 + n0 + nb;

    float acc[4][4];
#pragma unroll
    for (int i = 0; i < 4; ++i)
#pragma unroll
        for (int j = 0; j < 4; ++j) acc[i][j] = 0.f;

    for (int kk = 0; kk < C_DIM; kk += 16) {
        float4 a4 = *(const float4*)(arow + kk);
        As[ka + 0][ra] = a4.x;
        As[ka + 1][ra] = a4.y;
        As[ka + 2][ra] = a4.z;
        As[ka + 3][ra] = a4.w;
        *(float4*)&Bs[kb][nb] = *(const float4*)(bp + (size_t)kk * C4);
        __syncthreads();
#pragma unroll
        for (int kq = 0; kq < 16; ++kq) {
            float4 av = *(const float4*)&As[kq][ty << 2];
            float4 bv = *(const float4*)&Bs[kq][tx << 2];
            float aa[4] = {av.x, av.y, av.z, av.w};
            float bb[4] = {bv.x, bv.y, bv.z, bv.w};
#pragma unroll
            for (int i = 0; i < 4; ++i)
#pragma unroll
                for (int j = 0; j < 4; ++j) acc[i][j] += aa[i] * bb[j];
        }
        __syncthreads();
    }

    const int col0 = n0 + (tx << 2);
    float b4[4] = {bm1[col0], bm1[col0 + 1], bm1[col0 + 2], bm1[col0 + 3]};
#pragma unroll
    for (int i = 0; i < 4; ++i) {
        int row = m0 + (ty << 2) + i;
        ushort4 o;
        float vv;
        vv = acc[i][0] + b4[0]; o.x = f2bf(0.5f * vv * (1.f + erff(vv * 0.70710678118654752f)));
        vv = acc[i][1] + b4[1]; o.y = f2bf(0.5f * vv * (1.f + erff(vv * 0.70710678118654752f)));
        vv = acc[i][2] + b4[2]; o.z = f2bf(0.5f * vv * (1.f + erff(vv * 0.70710678118654752f)));
        vv = acc[i][3] + b4[3]; o.w = f2bf(0.5f * vv * (1.f + erff(vv * 0.70710678118654752f)));
        *(ushort4*)(hbuf + (size_t)row * C4 + col0) = o;
    }
}

// ---------------- K6: mlp2 GEMM ----------------
__global__ __launch_bounds__(256) void k_mlp2(
    const unsigned short* __restrict__ hbuf, const float* __restrict__ wm2,
    const float* __restrict__ bm2, float* __restrict__ mbuf)
{
    __shared__ float As[16][68];
    __shared__ float Bs[16][64];
    const int tx = threadIdx.x, ty = threadIdx.y;
    const int tid = ty * 16 + tx;
    const int m0 = blockIdx.y * 64;
    const int n0 = blockIdx.x * 64;
    const int ra = tid >> 2;
    const int ka = (tid & 3) << 2;
    const unsigned short* arow = hbuf + (size_t)(m0 + ra) * C4 + ka;
    const int kb = tid >> 4;
    const int nb = (tid & 15) << 2;
    const float* bp = wm2 + (size_t)kb * C_DIM + n0 + nb;

    float acc[4][4];
#pragma unroll
    for (int i = 0; i < 4; ++i)
#pragma unroll
        for (int j = 0; j < 4; ++j) acc[i][j] = 0.f;

    for (int kk = 0; kk < C4; kk += 16) {
        ushort4 a4 = *(const ushort4*)(arow + kk);
        As[ka + 0][ra] = bf2f(a4.x);
        As[ka + 1][ra] = bf2f(a4.y);
        As[ka + 2][ra] = bf2f(a4.z);
        As[ka + 3][ra] = bf2f(a4.w);
        *(float4*)&Bs[kb][nb] = *(const float4*)(bp + (size_t)kk * C_DIM);
        __syncthreads();
#pragma unroll
        for (int kq = 0; kq < 16; ++kq) {
            float4 av = *(const float4*)&As[kq][ty << 2];
            float4 bv = *(const float4*)&Bs[kq][tx << 2];
            float aa[4] = {av.x, av.y, av.z, av.w};
            float bb[4] = {bv.x, bv.y, bv.z, bv.w};
#pragma unroll
            for (int i = 0; i < 4; ++i)
#pragma unroll
                for (int j = 0; j < 4; ++j) acc[i][j] += aa[i] * bb[j];
        }
        __syncthreads();
    }

    const int col0 = n0 + (tx << 2);
    float4 bb4 = *(const float4*)(bm2 + col0);
#pragma unroll
    for (int i = 0; i < 4; ++i) {
        int row = m0 + (ty << 2) + i;
        float4 o;
        o.x = acc[i][0] + bb4.x;
        o.y = acc[i][1] + bb4.y;
        o.z = acc[i][2] + bb4.z;
        o.w = acc[i][3] + bb4.w;
        *(float4*)(mbuf + (size_t)row * C_DIM + col0) = o;
    }
}

// ---------------- K4/K7: out = resid + LayerNorm(src)*gamma + beta ----------------
__global__ __launch_bounds__(128) void k_ln_res(
    const float* __restrict__ src, const float* __restrict__ resid,
    const float* __restrict__ gamma, const float* __restrict__ beta,
    float* __restrict__ outp)
{
    const int row = blockIdx.x;
    const int t = threadIdx.x;
    const float* sr = src + (size_t)row * C_DIM;
    float v0 = sr[t], v1 = sr[t + 128], v2 = sr[t + 256];
    __shared__ float rs[128], rq[128];
    rs[t] = v0 + v1 + v2;
    rq[t] = v0 * v0 + v1 * v1 + v2 * v2;
    __syncthreads();
    for (int off = 64; off > 0; off >>= 1) {
        if (t < off) { rs[t] += rs[t + off]; rq[t] += rq[t + off]; }
        __syncthreads();
    }
    float mu = rs[0] * (1.f / 384.f);
    float var = rq[0] * (1.f / 384.f) - mu * mu;
    float rinv = rsqrtf(var + 1e-5f);
    const float* rr = resid + (size_t)row * C_DIM;
    float* orow = outp + (size_t)row * C_DIM;
    orow[t]       = rr[t]       + (v0 - mu) * rinv * gamma[t]       + beta[t];
    orow[t + 128] = rr[t + 128] + (v1 - mu) * rinv * gamma[t + 128] + beta[t + 128];
    orow[t + 256] = rr[t + 256] + (v2 - mu) * rinv * gamma[t + 256] + beta[t + 256];
}

extern "C" void kernel_launch(void* const* d_in, const int* in_sizes, int n_in,
                              void* d_out, int out_size, void* d_ws, size_t ws_size,
                              hipStream_t stream)
{
    const float* x     = (const float*)d_in[0];
    const float* wqkv  = (const float*)d_in[1];
    const float* bqkv  = (const float*)d_in[2];
    const float* wproj = (const float*)d_in[3];
    const float* bproj = (const float*)d_in[4];
    const float* btab  = (const float*)d_in[5];
    const float* g1    = (const float*)d_in[6];
    const float* b1    = (const float*)d_in[7];
    const float* g2    = (const float*)d_in[8];
    const float* b2    = (const float*)d_in[9];
    const float* wm1   = (const float*)d_in[10];
    const float* bm1   = (const float*)d_in[11];
    const float* wm2   = (const float*)d_in[12];
    const float* bm2   = (const float*)d_in[13];
    float* outp = (float*)d_out;

    const size_t LC = (size_t)L_TOK * C_DIM;   // 26,542,080 elements
    if (ws_size < 8 * LC) return;              // need 212.3 MB scratch
    char* ws = (char*)d_ws;
    unsigned short* qb  = (unsigned short*)ws;         // [0, 2LC) bytes
    unsigned short* kb  = qb + LC;                     // [2LC, 4LC)
    unsigned short* vb  = kb + LC;                     // [4LC, 6LC)
    unsigned short* aob = vb + LC;                     // [6LC, 8LC)
    float* x1 = (float*)ws;                            // reuses q+k region (dead)
    unsigned short* hbuf = (unsigned short*)(ws + 4 * LC);          // reuses v region
    float* mbuf = (float*)(ws + 4 * LC + (size_t)CHUNK * C4 * 2);   // after hbuf

    dim3 blk(16, 16);
    k_qkv<<<dim3(C3 / 64, L_TOK / 64), blk, 0, stream>>>(x, wqkv, bqkv, qb, kb, vb);
    k_attn<<<dim3(WH), dim3(128), 0, stream>>>(qb, kb, vb, btab, aob);
    k_proj<<<dim3(C_DIM / 64, L_TOK / 64), blk, 0, stream>>>(aob, wproj, bproj, outp);
    k_ln_res<<<dim3(L_TOK), dim3(128), 0, stream>>>(outp, x, g1, b1, x1);
    for (int c = 0; c < NCHUNK; ++c) {
        size_t r0 = (size_t)c * CHUNK;
        k_mlp1<<<dim3(C4 / 64, CHUNK / 64), blk, 0, stream>>>(x1 + r0 * C_DIM, wm1, bm1, hbuf);
        k_mlp2<<<dim3(C_DIM / 64, CHUNK / 64), blk, 0, stream>>>(hbuf, wm2, bm2, mbuf);
        k_ln_res<<<dim3(CHUNK), dim3(128), 0, stream>>>(mbuf, x1 + r0 * C_DIM, g2, b2, outp + r0 * C_DIM);
    }
    (void)in_sizes; (void)n_in; (void)out_size;
}

// Round 2
// 1564.113 us; speedup vs baseline: 2.7330x; 2.7330x over previous
//
#include <hip/hip_runtime.h>
#include <math.h>

#define L_TOK 69120
#define C_DIM 384
#define C3 1152
#define C4 1536
#define N_TOK 120
#define N_HEAD 12
#define BIAS_ROWS 2736
#define WH 6912
#define CHUNK 7680
#define NCHUNK 9

typedef __attribute__((ext_vector_type(8))) short short8;
typedef __attribute__((ext_vector_type(4))) float floatx4;

__device__ __forceinline__ unsigned short f2bf(float f) {
    union { float f; unsigned int u; } c; c.f = f;
    unsigned int u = c.u;
    return (unsigned short)((u + 0x7fffu + ((u >> 16) & 1u)) >> 16);
}
__device__ __forceinline__ float bf2f(unsigned short s) {
    union { unsigned int u; float f; } c; c.u = ((unsigned int)s) << 16;
    return c.f;
}

__device__ __forceinline__ void gl_lds16(const void* g, void* l) {
    __builtin_amdgcn_global_load_lds((const __attribute__((address_space(1))) unsigned int*)g,
                                     (__attribute__((address_space(3))) unsigned int*)l, 16, 0, 0);
}

// window-order row m = w_idx*120 + n  ->  global token index
__device__ __forceinline__ int win_to_global(int m) {
    int w_idx = m / N_TOK;
    int n = m - w_idx * N_TOK;
    int zw = w_idx / 144;
    int rem = w_idx - zw * 144;
    int hw = rem / 18;
    int ww = rem - hw * 18;
    int zl = n / 60;
    int r2 = n - zl * 60;
    int hl = r2 / 10;
    int wl = r2 - hl * 10;
    return ((zw * 2 + zl) * 48 + hw * 6 + hl) * 180 + ww * 10 + wl;
}

// -------- weight transpose+convert: W (K x N fp32) -> WT (N x K bf16) --------
__global__ __launch_bounds__(256) void k_wt(const float* __restrict__ W,
                                            unsigned short* __restrict__ WT, int K, int N) {
    __shared__ float tle[32][33];
    int n0 = blockIdx.x << 5, k0 = blockIdx.y << 5;
    for (int i = threadIdx.y; i < 32; i += 8)
        tle[i][threadIdx.x] = W[(size_t)(k0 + i) * N + n0 + threadIdx.x];
    __syncthreads();
    for (int i = threadIdx.y; i < 32; i += 8)
        WT[(size_t)(n0 + i) * K + k0 + threadIdx.x] = f2bf(tle[threadIdx.x][i]);
}

// -------- bias transpose: (2736 x 6912 fp32) -> (6912 x 2736 bf16) --------
__global__ __launch_bounds__(256) void k_bt(const float* __restrict__ Bsrc,
                                            unsigned short* __restrict__ BTt) {
    __shared__ float tle[32][33];
    int c0 = blockIdx.x << 5;
    int r0 = blockIdx.y << 5;
    for (int i = threadIdx.y; i < 32; i += 8) {
        int r = r0 + i;
        if (r < BIAS_ROWS) tle[i][threadIdx.x] = Bsrc[(size_t)r * WH + c0 + threadIdx.x];
    }
    __syncthreads();
    int rr = r0 + threadIdx.x;
    if (rr < BIAS_ROWS)
        for (int i = threadIdx.y; i < 32; i += 8)
            BTt[(size_t)(c0 + i) * BIAS_ROWS + rr] = f2bf(tle[threadIdx.x][i]);
}

// -------- shared MFMA mainloop (bf16 A, bf16 B^T, both via global_load_lds) --------
template <int K>
__device__ __forceinline__ void mfma_loop(const unsigned short* __restrict__ A,
                                          const unsigned short* __restrict__ BT,
                                          unsigned short* As, unsigned short* Bs,
                                          int m0, int n0, floatx4 acc[4][4]) {
    const int tid = threadIdx.x;
    const int wave = tid >> 6, lane = tid & 63;
    const int wm = (wave >> 1) << 6, wn = (wave & 1) << 6;
    const int lm = lane & 15, lq = lane >> 4;
    const int srow = lane >> 2, scol = (lane & 3) << 3;
    const unsigned short* ags = A + (size_t)(m0 + wave * 32 + srow) * K + scol;
    const unsigned short* bgs = BT + (size_t)(n0 + wave * 32 + srow) * K + scol;
    char* lA = (char*)As + wave * 2048;
    char* lB = (char*)Bs + wave * 2048;
    for (int kk = 0; kk < K; kk += 32) {
        gl_lds16(ags + kk, lA);
        gl_lds16(ags + (size_t)16 * K + kk, lA + 1024);
        gl_lds16(bgs + kk, lB);
        gl_lds16(bgs + (size_t)16 * K + kk, lB + 1024);
        __syncthreads();
        short8 af[4], bq[4];
#pragma unroll
        for (int i = 0; i < 4; ++i) af[i] = *(const short8*)(As + (wm + i * 16 + lm) * 32 + lq * 8);
#pragma unroll
        for (int j = 0; j < 4; ++j) bq[j] = *(const short8*)(Bs + (wn + j * 16 + lm) * 32 + lq * 8);
#pragma unroll
        for (int i = 0; i < 4; ++i)
#pragma unroll
            for (int j = 0; j < 4; ++j)
                acc[i][j] = __builtin_amdgcn_mfma_f32_16x16x32_bf16(af[i], bq[j], acc[i][j], 0, 0, 0);
        __syncthreads();
    }
}

// -------- K1: qkv MFMA GEMM; A = window-permuted fp32 x converted in-kernel --------
__global__ __launch_bounds__(256) void k_qkv(const float* __restrict__ x,
                                             const unsigned short* __restrict__ wqkvT,
                                             const float* __restrict__ bqkv,
                                             unsigned short* __restrict__ q,
                                             unsigned short* __restrict__ kbuf,
                                             unsigned short* __restrict__ vbuf) {
    __shared__ unsigned short As[128 * 40];   // padded stride 40 (A staged via ds_write)
    __shared__ unsigned short Bs[128 * 32];
    const int tid = threadIdx.x;
    const int wave = tid >> 6, lane = tid & 63;
    const int wm = (wave >> 1) << 6, wn = (wave & 1) << 6;
    const int lm = lane & 15, lq = lane >> 4;
    const int m0 = blockIdx.y << 7, n0 = blockIdx.x << 7;
    const int ar = tid >> 1, ah = (tid & 1) << 4;
    const float* xrow = x + (size_t)win_to_global(m0 + ar) * C_DIM + ah;
    unsigned short* aw = As + ar * 40 + ah;
    const int srow = lane >> 2, scol = (lane & 3) << 3;
    const unsigned short* bgs = wqkvT + (size_t)(n0 + wave * 32 + srow) * C_DIM + scol;
    char* lB = (char*)Bs + wave * 2048;

    floatx4 acc[4][4];
#pragma unroll
    for (int i = 0; i < 4; ++i)
#pragma unroll
        for (int j = 0; j < 4; ++j) acc[i][j] = (floatx4){0.f, 0.f, 0.f, 0.f};

    for (int kk = 0; kk < C_DIM; kk += 32) {
        gl_lds16(bgs + kk, lB);
        gl_lds16(bgs + (size_t)16 * C_DIM + kk, lB + 1024);
        float f[16];
        *(float4*)(f) = *(const float4*)(xrow + kk);
        *(float4*)(f + 4) = *(const float4*)(xrow + kk + 4);
        *(float4*)(f + 8) = *(const float4*)(xrow + kk + 8);
        *(float4*)(f + 12) = *(const float4*)(xrow + kk + 12);
        short8 s0, s1;
#pragma unroll
        for (int i = 0; i < 8; ++i) { s0[i] = (short)f2bf(f[i]); s1[i] = (short)f2bf(f[i + 8]); }
        *(short8*)aw = s0;
        *(short8*)(aw + 8) = s1;
        __syncthreads();
        short8 af[4], bq[4];
#pragma unroll
        for (int i = 0; i < 4; ++i) af[i] = *(const short8*)(As + (wm + i * 16 + lm) * 40 + lq * 8);
#pragma unroll
        for (int j = 0; j < 4; ++j) bq[j] = *(const short8*)(Bs + (wn + j * 16 + lm) * 32 + lq * 8);
#pragma unroll
        for (int i = 0; i < 4; ++i)
#pragma unroll
            for (int j = 0; j < 4; ++j)
                acc[i][j] = __builtin_amdgcn_mfma_f32_16x16x32_bf16(af[i], bq[j], acc[i][j], 0, 0, 0);
        __syncthreads();
    }

    const int sel = n0 / C_DIM;   // uniform: 128 | 384
    unsigned short* dst = (sel == 0) ? q : (sel == 1) ? kbuf : vbuf;
    const float scl = (sel == 0) ? 0.17677669529663687f : 1.0f;
#pragma unroll
    for (int i = 0; i < 4; ++i) {
        int rowb = m0 + wm + i * 16 + lq * 4;
        int wi[4], nn[4];
#pragma unroll
        for (int r = 0; r < 4; ++r) {
            int row = rowb + r;
            wi[r] = row / N_TOK;
            nn[r] = row - wi[r] * N_TOK;
        }
#pragma unroll
        for (int j = 0; j < 4; ++j) {
            int colg = n0 + wn + j * 16 + lm;
            float bias = bqkv[colg];
            int c2 = colg - sel * C_DIM;
            int head = c2 >> 5, dd = c2 & 31;
#pragma unroll
            for (int r = 0; r < 4; ++r)
                dst[(((size_t)(wi[r] * N_HEAD + head) * N_TOK + nn[r]) << 5) + dd] =
                    f2bf((acc[i][j][r] + bias) * scl);
        }
    }
}

// -------- K2: windowed attention; bias from transposed bf16 table --------
__global__ __launch_bounds__(128) void k_attn(const unsigned short* __restrict__ q,
                                              const unsigned short* __restrict__ k,
                                              const unsigned short* __restrict__ v,
                                              const unsigned short* __restrict__ btabT,
                                              unsigned short* __restrict__ ao) {
    const int wh = blockIdx.x;
    const int w = wh / N_HEAD;
    const int h = wh - w * N_HEAD;
    __shared__ float Ks[N_TOK][32];
    __shared__ float Vs[N_TOK][32];
    __shared__ float blds[BIAS_ROWS];
    const int t = threadIdx.x;
    const unsigned short* kbase = k + (size_t)wh * N_TOK * 32;
    const unsigned short* vbase = v + (size_t)wh * N_TOK * 32;
    for (int i = t; i < 960; i += 128) {
        ushort4 a = ((const ushort4*)kbase)[i];
        ushort4 b = ((const ushort4*)vbase)[i];
        int r = i >> 3, c = (i & 7) << 2;
        Ks[r][c] = bf2f(a.x); Ks[r][c + 1] = bf2f(a.y); Ks[r][c + 2] = bf2f(a.z); Ks[r][c + 3] = bf2f(a.w);
        Vs[r][c] = bf2f(b.x); Vs[r][c + 1] = bf2f(b.y); Vs[r][c + 2] = bf2f(b.z); Vs[r][c + 3] = bf2f(b.w);
    }
    const unsigned short* bptr = btabT + (size_t)wh * BIAS_ROWS;
    for (int i = t; i < BIAS_ROWS; i += 128) blds[i] = bf2f(bptr[i]);
    // q row loaded by ALL threads before the barrier (ao aliases this block's q slice)
    const int qn = (t < N_TOK) ? t : N_TOK - 1;
    const unsigned short* qrow = q + ((size_t)wh * N_TOK + qn) * 32;
    float qr[32];
#pragma unroll
    for (int i = 0; i < 8; ++i) {
        ushort4 a = ((const ushort4*)qrow)[i];
        qr[i * 4] = bf2f(a.x); qr[i * 4 + 1] = bf2f(a.y); qr[i * 4 + 2] = bf2f(a.z); qr[i * 4 + 3] = bf2f(a.w);
    }
    __syncthreads();

    if (t < N_TOK) {
        const int n = t;
        int zl = n / 60;
        int r2 = n - zl * 60;
        int hl = r2 / 10;
        int wl = r2 - hl * 10;
        const int pbase = zl * 684 + hl * 19 + wl + 9;
        float mx = -1e30f, l = 0.f;
        float o[32];
#pragma unroll
        for (int d = 0; d < 32; ++d) o[d] = 0.f;
        int z2 = 0, h2 = 0, w2 = 0;
        for (int m = 0; m < N_TOK; ++m) {
            int pos = pbase + z2 * 1368 + h2 * 114 - w2;
            float s = blds[pos];
#pragma unroll
            for (int d = 0; d < 32; ++d) s += qr[d] * Ks[m][d];
            float mnew = fmaxf(mx, s);
            float fac = __expf(mx - mnew);
            float p = __expf(s - mnew);
            l = l * fac + p;
#pragma unroll
            for (int d = 0; d < 32; ++d) o[d] = o[d] * fac + p * Vs[m][d];
            mx = mnew;
            if (++w2 == 10) { w2 = 0; if (++h2 == 6) { h2 = 0; ++z2; } }
        }
        float inv = 1.f / l;
        int r = h * 10 + n / 12;
        int c0 = (n - (n / 12) * 12) * 32;
        unsigned short* aor = ao + ((size_t)w * N_TOK + r) * C_DIM + c0;
#pragma unroll
        for (int d = 0; d < 32; ++d) aor[d] = f2bf(o[d] * inv);
    }
}

// -------- K3: proj MFMA GEMM + window reverse --------
__global__ __launch_bounds__(256) void k_proj(const unsigned short* __restrict__ ao,
                                              const unsigned short* __restrict__ wprojT,
                                              const float* __restrict__ bproj,
                                              float* __restrict__ p) {
    __shared__ unsigned short As[128 * 32];
    __shared__ unsigned short Bs[128 * 32];
    const int tid = threadIdx.x;
    const int wave = tid >> 6, lane = tid & 63;
    const int wm = (wave >> 1) << 6, wn = (wave & 1) << 6;
    const int lm = lane & 15, lq = lane >> 4;
    const int m0 = blockIdx.y << 7, n0 = blockIdx.x << 7;
    floatx4 acc[4][4];
#pragma unroll
    for (int i = 0; i < 4; ++i)
#pragma unroll
        for (int j = 0; j < 4; ++j) acc[i][j] = (floatx4){0.f, 0.f, 0.f, 0.f};
    mfma_loop<C_DIM>(ao, wprojT, As, Bs, m0, n0, acc);
#pragma unroll
    for (int i = 0; i < 4; ++i) {
        int rowb = m0 + wm + i * 16 + lq * 4;
        int gg[4];
#pragma unroll
        for (int r = 0; r < 4; ++r) gg[r] = win_to_global(rowb + r);
#pragma unroll
        for (int j = 0; j < 4; ++j) {
            int colg = n0 + wn + j * 16 + lm;
            float bias = bproj[colg];
#pragma unroll
            for (int r = 0; r < 4; ++r)
                p[(size_t)gg[r] * C_DIM + colg] = acc[i][j][r] + bias;
        }
    }
}

// -------- K5: mlp1 MFMA GEMM + exact GELU -> bf16 --------
__global__ __launch_bounds__(256) void k_mlp1(const unsigned short* __restrict__ x1b,
                                              const unsigned short* __restrict__ wm1T,
                                              const float* __restrict__ bm1,
                                              unsigned short* __restrict__ hbuf) {
    __shared__ unsigned short As[128 * 32];
    __shared__ unsigned short Bs[128 * 32];
    const int tid = threadIdx.x;
    const int wave = tid >> 6, lane = tid & 63;
    const int wm = (wave >> 1) << 6, wn = (wave & 1) << 6;
    const int lm = lane & 15, lq = lane >> 4;
    const int m0 = blockIdx.y << 7, n0 = blockIdx.x << 7;
    floatx4 acc[4][4];
#pragma unroll
    for (int i = 0; i < 4; ++i)
#pragma unroll
        for (int j = 0; j < 4; ++j) acc[i][j] = (floatx4){0.f, 0.f, 0.f, 0.f};
    mfma_loop<C_DIM>(x1b, wm1T, As, Bs, m0, n0, acc);
#pragma unroll
    for (int i = 0; i < 4; ++i) {
        int rowb = m0 + wm + i * 16 + lq * 4;
#pragma unroll
        for (int j = 0; j < 4; ++j) {
            int colg = n0 + wn + j * 16 + lm;
            float bias = bm1[colg];
#pragma unroll
            for (int r = 0; r < 4; ++r) {
                float vv = acc[i][j][r] + bias;
                float ge = 0.5f * vv * (1.f + erff(vv * 0.70710678118654752f));
                hbuf[(size_t)(rowb + r) * C4 + colg] = f2bf(ge);
            }
        }
    }
}

// -------- K6: mlp2 MFMA GEMM -> fp32 --------
__global__ __launch_bounds__(256) void k_mlp2(const unsigned short* __restrict__ hbuf,
                                              const unsigned short* __restrict__ wm2T,
                                              const float* __restrict__ bm2,
                                              float* __restrict__ mbuf) {
    __shared__ unsigned short As[128 * 32];
    __shared__ unsigned short Bs[128 * 32];
    const int tid = threadIdx.x;
    const int wave = tid >> 6, lane = tid & 63;
    const int wm = (wave >> 1) << 6, wn = (wave & 1) << 6;
    const int lm = lane & 15, lq = lane >> 4;
    const int m0 = blockIdx.y << 7, n0 = blockIdx.x << 7;
    floatx4 acc[4][4];
#pragma unroll
    for (int i = 0; i < 4; ++i)
#pragma unroll
        for (int j = 0; j < 4; ++j) acc[i][j] = (floatx4){0.f, 0.f, 0.f, 0.f};
    mfma_loop<C4>(hbuf, wm2T, As, Bs, m0, n0, acc);
#pragma unroll
    for (int i = 0; i < 4; ++i) {
        int rowb = m0 + wm + i * 16 + lq * 4;
#pragma unroll
        for (int j = 0; j < 4; ++j) {
            int colg = n0 + wn + j * 16 + lm;
            float bias = bm2[colg];
#pragma unroll
            for (int r = 0; r < 4; ++r)
                mbuf[(size_t)(rowb + r) * C_DIM + colg] = acc[i][j][r] + bias;
        }
    }
}

// -------- K4/K7: out = resid + LayerNorm(src)*g + b  (+ optional bf16 copy) --------
__global__ __launch_bounds__(128) void k_ln_res(const float* __restrict__ src,
                                                const float* __restrict__ resid,
                                                const float* __restrict__ gamma,
                                                const float* __restrict__ beta,
                                                float* __restrict__ outp,
                                                unsigned short* __restrict__ out_bf) {
    const int row = blockIdx.x;
    const int t = threadIdx.x;
    const float* sr = src + (size_t)row * C_DIM;
    float v0 = sr[t], v1 = sr[t + 128], v2 = sr[t + 256];
    __shared__ float rs[128], rq[128];
    rs[t] = v0 + v1 + v2;
    rq[t] = v0 * v0 + v1 * v1 + v2 * v2;
    __syncthreads();
    for (int off = 64; off > 0; off >>= 1) {
        if (t < off) { rs[t] += rs[t + off]; rq[t] += rq[t + off]; }
        __syncthreads();
    }
    float mu = rs[0] * (1.f / 384.f);
    float var = rq[0] * (1.f / 384.f) - mu * mu;
    float rinv = rsqrtf(var + 1e-5f);
    const float* rr = resid + (size_t)row * C_DIM;
    float* orow = outp + (size_t)row * C_DIM;
    float y0 = rr[t]       + (v0 - mu) * rinv * gamma[t]       + beta[t];
    float y1 = rr[t + 128] + (v1 - mu) * rinv * gamma[t + 128] + beta[t + 128];
    float y2 = rr[t + 256] + (v2 - mu) * rinv * gamma[t + 256] + beta[t + 256];
    orow[t] = y0; orow[t + 128] = y1; orow[t + 256] = y2;
    if (out_bf) {
        unsigned short* ob = out_bf + (size_t)row * C_DIM;
        ob[t] = f2bf(y0); ob[t + 128] = f2bf(y1); ob[t + 256] = f2bf(y2);
    }
}

extern "C" void kernel_launch(void* const* d_in, const int* in_sizes, int n_in,
                              void* d_out, int out_size, void* d_ws, size_t ws_size,
                              hipStream_t stream) {
    const float* x     = (const float*)d_in[0];
    const float* wqkv  = (const float*)d_in[1];
    const float* bqkv  = (const float*)d_in[2];
    const float* wproj = (const float*)d_in[3];
    const float* bproj = (const float*)d_in[4];
    const float* btab  = (const float*)d_in[5];
    const float* g1    = (const float*)d_in[6];
    const float* b1    = (const float*)d_in[7];
    const float* g2    = (const float*)d_in[8];
    const float* b2    = (const float*)d_in[9];
    const float* wm1   = (const float*)d_in[10];
    const float* bm1   = (const float*)d_in[11];
    const float* wm2   = (const float*)d_in[12];
    const float* bm2   = (const float*)d_in[13];
    float* outp = (float*)d_out;

    const size_t LC = (size_t)L_TOK * C_DIM;          // elements
    if (ws_size < 8 * LC) return;                     // 212.3 MB (verified available)
    char* ws = (char*)d_ws;
    const size_t QB = LC * 2;                         // bytes of one bf16 L x C buffer
    unsigned short* qb  = (unsigned short*)ws;                    // [0, QB)
    unsigned short* kb  = (unsigned short*)(ws + QB);             // [QB, 2QB)
    unsigned short* vb  = (unsigned short*)(ws + 2 * QB);         // [2QB, 3QB)
    unsigned short* btT = (unsigned short*)(ws + 3 * QB);         // 37.8 MB, dead after attn
    size_t wof = 3 * QB + (size_t)WH * BIAS_ROWS * 2;
    unsigned short* wqkvT = (unsigned short*)(ws + wof);
    unsigned short* wprojT = wqkvT + (size_t)C3 * C_DIM;
    unsigned short* wm1T   = wprojT + (size_t)C_DIM * C_DIM;
    unsigned short* wm2T   = wm1T + (size_t)C_DIM * C4;
    unsigned short* aob = qb;                                     // reuses q (exact alias, safe)
    float* proj = (float*)(ws + QB);                              // 4 units over k,v (dead)
    float* x1   = proj;                                           // LN1 in-place
    unsigned short* x1b = qb;                                     // over ao (dead after proj)
    unsigned short* hbuf = (unsigned short*)(ws + 3 * QB);        // over btT (dead after attn)
    float* mbuf = (float*)(ws + 3 * QB + (size_t)CHUNK * C4 * 2);

    dim3 tb(32, 8);
    k_wt<<<dim3(C3 / 32, C_DIM / 32), tb, 0, stream>>>(wqkv, wqkvT, C_DIM, C3);
    k_wt<<<dim3(C_DIM / 32, C_DIM / 32), tb, 0, stream>>>(wproj, wprojT, C_DIM, C_DIM);
    k_wt<<<dim3(C4 / 32, C_DIM / 32), tb, 0, stream>>>(wm1, wm1T, C_DIM, C4);
    k_wt<<<dim3(C_DIM / 32, C4 / 32), tb, 0, stream>>>(wm2, wm2T, C4, C_DIM);
    k_bt<<<dim3(WH / 32, (BIAS_ROWS + 31) / 32), tb, 0, stream>>>(btab, btT);

    k_qkv<<<dim3(C3 / 128, L_TOK / 128), dim3(256), 0, stream>>>(x, wqkvT, bqkv, qb, kb, vb);
    k_attn<<<dim3(WH), dim3(128), 0, stream>>>(qb, kb, vb, btT, aob);
    k_proj<<<dim3(C_DIM / 128, L_TOK / 128), dim3(256), 0, stream>>>(aob, wprojT, bproj, proj);
    k_ln_res<<<dim3(L_TOK), dim3(128), 0, stream>>>(proj, x, g1, b1, x1, x1b);
    for (int c = 0; c < NCHUNK; ++c) {
        size_t r0 = (size_t)c * CHUNK;
        k_mlp1<<<dim3(C4 / 128, CHUNK / 128), dim3(256), 0, stream>>>(x1b + r0 * C_DIM, wm1T, bm1, hbuf);
        k_mlp2<<<dim3(C_DIM / 128, CHUNK / 128), dim3(256), 0, stream>>>(hbuf, wm2T, bm2, mbuf);
        k_ln_res<<<dim3(CHUNK), dim3(128), 0, stream>>>(mbuf, x1 + r0 * C_DIM, g2, b2, outp + r0 * C_DIM, (unsigned short*)nullptr);
    }
    (void)in_sizes; (void)n_in; (void)out_size;
}

// Round 3
// 1274.289 us; speedup vs baseline: 3.3545x; 1.2274x over previous
//
#include <hip/hip_runtime.h>
#include <math.h>

#define L_TOK 69120
#define C_DIM 384
#define C3 1152
#define C4 1536
#define N_TOK 120
#define N_HEAD 12
#define BIAS_ROWS 2736
#define WH 6912
#define CHUNK 7680
#define NCHUNK 9

typedef __attribute__((ext_vector_type(8))) short short8;
typedef __attribute__((ext_vector_type(4))) float floatx4;

__device__ __forceinline__ unsigned short f2bf(float f) {
    union { float f; unsigned int u; } c; c.f = f;
    unsigned int u = c.u;
    return (unsigned short)((u + 0x7fffu + ((u >> 16) & 1u)) >> 16);
}
__device__ __forceinline__ float bf2f(unsigned short s) {
    union { unsigned int u; float f; } c; c.u = ((unsigned int)s) << 16;
    return c.f;
}

__device__ __forceinline__ void gl_lds16(const void* g, void* l) {
    __builtin_amdgcn_global_load_lds((const __attribute__((address_space(1))) unsigned int*)g,
                                     (__attribute__((address_space(3))) unsigned int*)l, 16, 0, 0);
}

// window-order row m = w_idx*120 + n  ->  global token index
__device__ __forceinline__ int win_to_global(int m) {
    int w_idx = m / N_TOK;
    int n = m - w_idx * N_TOK;
    int zw = w_idx / 144;
    int rem = w_idx - zw * 144;
    int hw = rem / 18;
    int ww = rem - hw * 18;
    int zl = n / 60;
    int r2 = n - zl * 60;
    int hl = r2 / 10;
    int wl = r2 - hl * 10;
    return ((zw * 2 + zl) * 48 + hw * 6 + hl) * 180 + ww * 10 + wl;
}

// -------- weight transpose+convert: W (K x N fp32) -> WT (N x K bf16) --------
__global__ __launch_bounds__(256) void k_wt(const float* __restrict__ W,
                                            unsigned short* __restrict__ WT, int K, int N) {
    __shared__ float tle[32][33];
    int n0 = blockIdx.x << 5, k0 = blockIdx.y << 5;
    for (int i = threadIdx.y; i < 32; i += 8)
        tle[i][threadIdx.x] = W[(size_t)(k0 + i) * N + n0 + threadIdx.x];
    __syncthreads();
    for (int i = threadIdx.y; i < 32; i += 8)
        WT[(size_t)(n0 + i) * K + k0 + threadIdx.x] = f2bf(tle[threadIdx.x][i]);
}

// -------- bias transpose: (2736 x 6912 fp32) -> (6912 x 2736 bf16) --------
__global__ __launch_bounds__(256) void k_bt(const float* __restrict__ Bsrc,
                                            unsigned short* __restrict__ BTt) {
    __shared__ float tle[32][33];
    int c0 = blockIdx.x << 5;
    int r0 = blockIdx.y << 5;
    for (int i = threadIdx.y; i < 32; i += 8) {
        int r = r0 + i;
        if (r < BIAS_ROWS) tle[i][threadIdx.x] = Bsrc[(size_t)r * WH + c0 + threadIdx.x];
    }
    __syncthreads();
    int rr = r0 + threadIdx.x;
    if (rr < BIAS_ROWS)
        for (int i = threadIdx.y; i < 32; i += 8)
            BTt[(size_t)(c0 + i) * BIAS_ROWS + rr] = f2bf(tle[threadIdx.x][i]);
}

// -------- shared MFMA mainloop (bf16 A, bf16 B^T, both via global_load_lds) --------
template <int K>
__device__ __forceinline__ void mfma_loop(const unsigned short* __restrict__ A,
                                          const unsigned short* __restrict__ BT,
                                          unsigned short* As, unsigned short* Bs,
                                          int m0, int n0, floatx4 acc[4][4]) {
    const int tid = threadIdx.x;
    const int wave = tid >> 6, lane = tid & 63;
    const int wm = (wave >> 1) << 6, wn = (wave & 1) << 6;
    const int lm = lane & 15, lq = lane >> 4;
    const int srow = lane >> 2, scol = (lane & 3) << 3;
    const unsigned short* ags = A + (size_t)(m0 + wave * 32 + srow) * K + scol;
    const unsigned short* bgs = BT + (size_t)(n0 + wave * 32 + srow) * K + scol;
    char* lA = (char*)As + wave * 2048;
    char* lB = (char*)Bs + wave * 2048;
    for (int kk = 0; kk < K; kk += 32) {
        gl_lds16(ags + kk, lA);
        gl_lds16(ags + (size_t)16 * K + kk, lA + 1024);
        gl_lds16(bgs + kk, lB);
        gl_lds16(bgs + (size_t)16 * K + kk, lB + 1024);
        __syncthreads();
        short8 af[4], bq[4];
#pragma unroll
        for (int i = 0; i < 4; ++i) af[i] = *(const short8*)(As + (wm + i * 16 + lm) * 32 + lq * 8);
#pragma unroll
        for (int j = 0; j < 4; ++j) bq[j] = *(const short8*)(Bs + (wn + j * 16 + lm) * 32 + lq * 8);
#pragma unroll
        for (int i = 0; i < 4; ++i)
#pragma unroll
            for (int j = 0; j < 4; ++j)
                acc[i][j] = __builtin_amdgcn_mfma_f32_16x16x32_bf16(af[i], bq[j], acc[i][j], 0, 0, 0);
        __syncthreads();
    }
}

// -------- K1: qkv MFMA GEMM; A = window-permuted fp32 x converted in-kernel --------
// q: (wh, n, d) scaled; k: (wh, n, d); v: TRANSPOSED (wh, d, n) for attn B-frags
__global__ __launch_bounds__(256) void k_qkv(const float* __restrict__ x,
                                             const unsigned short* __restrict__ wqkvT,
                                             const float* __restrict__ bqkv,
                                             unsigned short* __restrict__ q,
                                             unsigned short* __restrict__ kbuf,
                                             unsigned short* __restrict__ vbuf) {
    __shared__ unsigned short As[128 * 40];
    __shared__ unsigned short Bs[128 * 32];
    const int tid = threadIdx.x;
    const int wave = tid >> 6, lane = tid & 63;
    const int wm = (wave >> 1) << 6, wn = (wave & 1) << 6;
    const int lm = lane & 15, lq = lane >> 4;
    const int m0 = blockIdx.y << 7, n0 = blockIdx.x << 7;
    const int ar = tid >> 1, ah = (tid & 1) << 4;
    const float* xrow = x + (size_t)win_to_global(m0 + ar) * C_DIM + ah;
    unsigned short* aw = As + ar * 40 + ah;
    const int srow = lane >> 2, scol = (lane & 3) << 3;
    const unsigned short* bgs = wqkvT + (size_t)(n0 + wave * 32 + srow) * C_DIM + scol;
    char* lB = (char*)Bs + wave * 2048;

    floatx4 acc[4][4];
#pragma unroll
    for (int i = 0; i < 4; ++i)
#pragma unroll
        for (int j = 0; j < 4; ++j) acc[i][j] = (floatx4){0.f, 0.f, 0.f, 0.f};

    for (int kk = 0; kk < C_DIM; kk += 32) {
        gl_lds16(bgs + kk, lB);
        gl_lds16(bgs + (size_t)16 * C_DIM + kk, lB + 1024);
        float f[16];
        *(float4*)(f) = *(const float4*)(xrow + kk);
        *(float4*)(f + 4) = *(const float4*)(xrow + kk + 4);
        *(float4*)(f + 8) = *(const float4*)(xrow + kk + 8);
        *(float4*)(f + 12) = *(const float4*)(xrow + kk + 12);
        short8 s0, s1;
#pragma unroll
        for (int i = 0; i < 8; ++i) { s0[i] = (short)f2bf(f[i]); s1[i] = (short)f2bf(f[i + 8]); }
        *(short8*)aw = s0;
        *(short8*)(aw + 8) = s1;
        __syncthreads();
        short8 af[4], bq[4];
#pragma unroll
        for (int i = 0; i < 4; ++i) af[i] = *(const short8*)(As + (wm + i * 16 + lm) * 40 + lq * 8);
#pragma unroll
        for (int j = 0; j < 4; ++j) bq[j] = *(const short8*)(Bs + (wn + j * 16 + lm) * 32 + lq * 8);
#pragma unroll
        for (int i = 0; i < 4; ++i)
#pragma unroll
            for (int j = 0; j < 4; ++j)
                acc[i][j] = __builtin_amdgcn_mfma_f32_16x16x32_bf16(af[i], bq[j], acc[i][j], 0, 0, 0);
        __syncthreads();
    }

    const int sel = n0 / C_DIM;   // uniform: 128 | 384
    unsigned short* dst = (sel == 0) ? q : (sel == 1) ? kbuf : vbuf;
    const float scl = (sel == 0) ? 0.17677669529663687f : 1.0f;
#pragma unroll
    for (int i = 0; i < 4; ++i) {
        int rowb = m0 + wm + i * 16 + lq * 4;
        int wi[4], nn[4];
#pragma unroll
        for (int r = 0; r < 4; ++r) {
            int row = rowb + r;
            wi[r] = row / N_TOK;
            nn[r] = row - wi[r] * N_TOK;
        }
#pragma unroll
        for (int j = 0; j < 4; ++j) {
            int colg = n0 + wn + j * 16 + lm;
            float bias = bqkv[colg];
            int c2 = colg - sel * C_DIM;
            int head = c2 >> 5, dd = c2 & 31;
#pragma unroll
            for (int r = 0; r < 4; ++r) {
                unsigned short val = f2bf((acc[i][j][r] + bias) * scl);
                if (sel == 2)
                    dst[((size_t)(wi[r] * N_HEAD + head) * 32 + dd) * N_TOK + nn[r]] = val;
                else
                    dst[(((size_t)(wi[r] * N_HEAD + head) * N_TOK + nn[r]) << 5) + dd] = val;
            }
        }
    }
}

// -------- K2: MFMA windowed attention (S^T = K·Q^T trick) --------
// block = one (window, head), 4 waves; wave handles q-tiles {wave, wave+4}.
// S^T C-layout: lane holds query col=lane&15, keys rows quad*4+reg (+16*kt)
// -> softmax = in-lane reduce + shfl_xor(16,32). P via per-wave LDS -> A-frags.
__global__ __launch_bounds__(256) void k_attn(const unsigned short* __restrict__ q,
                                              const unsigned short* __restrict__ k,
                                              const unsigned short* __restrict__ vt,
                                              const unsigned short* __restrict__ btabT,
                                              unsigned short* __restrict__ ao) {
    const int wh = blockIdx.x;
    const int w = wh / N_HEAD;
    const int h = wh - w * N_HEAD;
    __shared__ float blds[BIAS_ROWS];
    __shared__ __align__(16) unsigned short plds[4][16 * 136];
    const int tid = threadIdx.x;
    const unsigned short* bptr = btabT + (size_t)wh * BIAS_ROWS;
    for (int i = tid; i < BIAS_ROWS; i += 256) blds[i] = bf2f(bptr[i]);
    __syncthreads();

    const int wave = tid >> 6, lane = tid & 63;
    const int lm = lane & 15, lq = lane >> 4;
    const unsigned short* kwh = k + (size_t)wh * N_TOK * 32;
    const unsigned short* qwh = q + (size_t)wh * N_TOK * 32;
    const unsigned short* vwh = vt + (size_t)wh * 32 * N_TOK;
    unsigned short* pl = plds[wave];

    // K A-fragments, reused for both q-tiles (keys 16kt+lm, d = lq*8..+7)
    short8 kfr[8];
#pragma unroll
    for (int kt = 0; kt < 8; ++kt)
        kfr[kt] = *(const short8*)(kwh + (size_t)(kt * 16 + lm) * 32 + lq * 8);

    // bias key-offsets: depend only on (kt, lq); reg deltas -1,-2,-3 with
    // w2-wrap (+123 step) when k0%10==8 (k0 = 16kt+4lq is always %4==0)
    int p0v[8], d2v[8], d3v[8];
#pragma unroll
    for (int kt = 0; kt < 8; ++kt) {
        int k0 = kt * 16 + lq * 4;
        int z2 = (k0 >= 60) ? 1 : 0;
        int k0m = k0 - 60 * z2;
        int h2 = k0m / 10;
        int w2 = k0m - 10 * h2;
        p0v[kt] = z2 * 1368 + h2 * 114 - w2;
        d2v[kt] = (w2 == 8) ? 122 : -2;
        d3v[kt] = (w2 == 8) ? 121 : -3;
    }

    for (int qi = 0; qi < 2; ++qi) {
        const int qt = wave + 4 * qi;
        short8 qfr = *(const short8*)(qwh + (size_t)(qt * 16 + lm) * 32 + lq * 8);
        floatx4 sc[8];
#pragma unroll
        for (int kt = 0; kt < 8; ++kt)
            sc[kt] = __builtin_amdgcn_mfma_f32_16x16x32_bf16(kfr[kt], qfr,
                                                             (floatx4){0.f, 0.f, 0.f, 0.f}, 0, 0, 0);
        // earth-position bias + key-padding mask
        int qg = qt * 16 + lm;
        int zl = qg / 60;
        int r2 = qg - zl * 60;
        int hl = r2 / 10;
        int wl = r2 - hl * 10;
        int pbase = zl * 684 + hl * 19 + wl + 9;
        pbase = min(pbase, 797);        // keeps padded queries in-range
#pragma unroll
        for (int kt = 0; kt < 8; ++kt) {
            if (kt == 7 && lq >= 2) {
                sc[kt] = (floatx4){-1e30f, -1e30f, -1e30f, -1e30f};
            } else {
                int base = pbase + p0v[kt];
                sc[kt][0] += blds[base];
                sc[kt][1] += blds[base - 1];
                sc[kt][2] += blds[base + d2v[kt]];
                sc[kt][3] += blds[base + d3v[kt]];
            }
        }
        // softmax over keys: in-lane (32 vals) then across quads
        float mx = -1e30f;
#pragma unroll
        for (int kt = 0; kt < 8; ++kt)
#pragma unroll
            for (int r = 0; r < 4; ++r) mx = fmaxf(mx, sc[kt][r]);
        mx = fmaxf(mx, __shfl_xor(mx, 16, 64));
        mx = fmaxf(mx, __shfl_xor(mx, 32, 64));
        float l = 0.f;
#pragma unroll
        for (int kt = 0; kt < 8; ++kt)
#pragma unroll
            for (int r = 0; r < 4; ++r) {
                float p = __expf(sc[kt][r] - mx);
                sc[kt][r] = p;
                l += p;
            }
        l += __shfl_xor(l, 16, 64);
        l += __shfl_xor(l, 32, 64);
        float inv = 1.f / l;
        // P (normalized, bf16) -> per-wave LDS [query=lm][key], stride 136 shorts
#pragma unroll
        for (int kt = 0; kt < 8; ++kt) {
            uint2 pk;
            pk.x = (unsigned int)f2bf(sc[kt][0] * inv) | ((unsigned int)f2bf(sc[kt][1] * inv) << 16);
            pk.y = (unsigned int)f2bf(sc[kt][2] * inv) | ((unsigned int)f2bf(sc[kt][3] * inv) << 16);
            *(uint2*)(pl + lm * 136 + kt * 16 + lq * 4) = pk;
        }
        // PV: A = P (from LDS), B = V^T rows (contiguous)
        floatx4 oac[2] = {(floatx4){0.f, 0.f, 0.f, 0.f}, (floatx4){0.f, 0.f, 0.f, 0.f}};
#pragma unroll
        for (int ks = 0; ks < 4; ++ks) {
            short8 af = *(const short8*)(pl + lm * 136 + ks * 32 + lq * 8);
#pragma unroll
            for (int ct = 0; ct < 2; ++ct) {
                short8 bf = *(const short8*)(vwh + (size_t)(ct * 16 + lm) * N_TOK + ks * 32 + lq * 8);
                oac[ct] = __builtin_amdgcn_mfma_f32_16x16x32_bf16(af, bf, oac[ct], 0, 0, 0);
            }
        }
        // store in the reference's head-major reshape; skip padded queries
#pragma unroll
        for (int r = 0; r < 4; ++r) {
            int qg2 = qt * 16 + lq * 4 + r;
            if (qg2 < N_TOK) {
                int rq = qg2 / 12;
                int rr = h * 10 + rq;
                int cc = (qg2 - rq * 12) * 32;
#pragma unroll
                for (int ct = 0; ct < 2; ++ct)
                    ao[((size_t)w * N_TOK + rr) * C_DIM + cc + ct * 16 + lm] = f2bf(oac[ct][r]);
            }
        }
    }
}

// -------- K3: proj MFMA GEMM + window reverse --------
__global__ __launch_bounds__(256) void k_proj(const unsigned short* __restrict__ ao,
                                              const unsigned short* __restrict__ wprojT,
                                              const float* __restrict__ bproj,
                                              float* __restrict__ p) {
    __shared__ unsigned short As[128 * 32];
    __shared__ unsigned short Bs[128 * 32];
    const int tid = threadIdx.x;
    const int wave = tid >> 6, lane = tid & 63;
    const int wm = (wave >> 1) << 6, wn = (wave & 1) << 6;
    const int lm = lane & 15, lq = lane >> 4;
    const int m0 = blockIdx.y << 7, n0 = blockIdx.x << 7;
    floatx4 acc[4][4];
#pragma unroll
    for (int i = 0; i < 4; ++i)
#pragma unroll
        for (int j = 0; j < 4; ++j) acc[i][j] = (floatx4){0.f, 0.f, 0.f, 0.f};
    mfma_loop<C_DIM>(ao, wprojT, As, Bs, m0, n0, acc);
#pragma unroll
    for (int i = 0; i < 4; ++i) {
        int rowb = m0 + wm + i * 16 + lq * 4;
        int gg[4];
#pragma unroll
        for (int r = 0; r < 4; ++r) gg[r] = win_to_global(rowb + r);
#pragma unroll
        for (int j = 0; j < 4; ++j) {
            int colg = n0 + wn + j * 16 + lm;
            float bias = bproj[colg];
#pragma unroll
            for (int r = 0; r < 4; ++r)
                p[(size_t)gg[r] * C_DIM + colg] = acc[i][j][r] + bias;
        }
    }
}

// -------- K5: mlp1 MFMA GEMM + exact GELU -> bf16 --------
__global__ __launch_bounds__(256) void k_mlp1(const unsigned short* __restrict__ x1b,
                                              const unsigned short* __restrict__ wm1T,
                                              const float* __restrict__ bm1,
                                              unsigned short* __restrict__ hbuf) {
    __shared__ unsigned short As[128 * 32];
    __shared__ unsigned short Bs[128 * 32];
    const int tid = threadIdx.x;
    const int wave = tid >> 6, lane = tid & 63;
    const int wm = (wave >> 1) << 6, wn = (wave & 1) << 6;
    const int lm = lane & 15, lq = lane >> 4;
    const int m0 = blockIdx.y << 7, n0 = blockIdx.x << 7;
    floatx4 acc[4][4];
#pragma unroll
    for (int i = 0; i < 4; ++i)
#pragma unroll
        for (int j = 0; j < 4; ++j) acc[i][j] = (floatx4){0.f, 0.f, 0.f, 0.f};
    mfma_loop<C_DIM>(x1b, wm1T, As, Bs, m0, n0, acc);
#pragma unroll
    for (int i = 0; i < 4; ++i) {
        int rowb = m0 + wm + i * 16 + lq * 4;
#pragma unroll
        for (int j = 0; j < 4; ++j) {
            int colg = n0 + wn + j * 16 + lm;
            float bias = bm1[colg];
#pragma unroll
            for (int r = 0; r < 4; ++r) {
                float vv = acc[i][j][r] + bias;
                float ge = 0.5f * vv * (1.f + erff(vv * 0.70710678118654752f));
                hbuf[(size_t)(rowb + r) * C4 + colg] = f2bf(ge);
            }
        }
    }
}

// -------- K6: mlp2 MFMA GEMM -> fp32 --------
__global__ __launch_bounds__(256) void k_mlp2(const unsigned short* __restrict__ hbuf,
                                              const unsigned short* __restrict__ wm2T,
                                              const float* __restrict__ bm2,
                                              float* __restrict__ mbuf) {
    __shared__ unsigned short As[128 * 32];
    __shared__ unsigned short Bs[128 * 32];
    const int tid = threadIdx.x;
    const int wave = tid >> 6, lane = tid & 63;
    const int wm = (wave >> 1) << 6, wn = (wave & 1) << 6;
    const int lm = lane & 15, lq = lane >> 4;
    const int m0 = blockIdx.y << 7, n0 = blockIdx.x << 7;
    floatx4 acc[4][4];
#pragma unroll
    for (int i = 0; i < 4; ++i)
#pragma unroll
        for (int j = 0; j < 4; ++j) acc[i][j] = (floatx4){0.f, 0.f, 0.f, 0.f};
    mfma_loop<C4>(hbuf, wm2T, As, Bs, m0, n0, acc);
#pragma unroll
    for (int i = 0; i < 4; ++i) {
        int rowb = m0 + wm + i * 16 + lq * 4;
#pragma unroll
        for (int j = 0; j < 4; ++j) {
            int colg = n0 + wn + j * 16 + lm;
            float bias = bm2[colg];
#pragma unroll
            for (int r = 0; r < 4; ++r)
                mbuf[(size_t)(rowb + r) * C_DIM + colg] = acc[i][j][r] + bias;
        }
    }
}

// -------- K4/K7: out = resid + LayerNorm(src)*g + b  (+ optional bf16 copy) --------
__global__ __launch_bounds__(128) void k_ln_res(const float* __restrict__ src,
                                                const float* __restrict__ resid,
                                                const float* __restrict__ gamma,
                                                const float* __restrict__ beta,
                                                float* __restrict__ outp,
                                                unsigned short* __restrict__ out_bf) {
    const int row = blockIdx.x;
    const int t = threadIdx.x;
    const float* sr = src + (size_t)row * C_DIM;
    float v0 = sr[t], v1 = sr[t + 128], v2 = sr[t + 256];
    __shared__ float rs[128], rq[128];
    rs[t] = v0 + v1 + v2;
    rq[t] = v0 * v0 + v1 * v1 + v2 * v2;
    __syncthreads();
    for (int off = 64; off > 0; off >>= 1) {
        if (t < off) { rs[t] += rs[t + off]; rq[t] += rq[t + off]; }
        __syncthreads();
    }
    float mu = rs[0] * (1.f / 384.f);
    float var = rq[0] * (1.f / 384.f) - mu * mu;
    float rinv = rsqrtf(var + 1e-5f);
    const float* rr = resid + (size_t)row * C_DIM;
    float* orow = outp + (size_t)row * C_DIM;
    float y0 = rr[t]       + (v0 - mu) * rinv * gamma[t]       + beta[t];
    float y1 = rr[t + 128] + (v1 - mu) * rinv * gamma[t + 128] + beta[t + 128];
    float y2 = rr[t + 256] + (v2 - mu) * rinv * gamma[t + 256] + beta[t + 256];
    orow[t] = y0; orow[t + 128] = y1; orow[t + 256] = y2;
    if (out_bf) {
        unsigned short* ob = out_bf + (size_t)row * C_DIM;
        ob[t] = f2bf(y0); ob[t + 128] = f2bf(y1); ob[t + 256] = f2bf(y2);
    }
}

extern "C" void kernel_launch(void* const* d_in, const int* in_sizes, int n_in,
                              void* d_out, int out_size, void* d_ws, size_t ws_size,
                              hipStream_t stream) {
    const float* x     = (const float*)d_in[0];
    const float* wqkv  = (const float*)d_in[1];
    const float* bqkv  = (const float*)d_in[2];
    const float* wproj = (const float*)d_in[3];
    const float* bproj = (const float*)d_in[4];
    const float* btab  = (const float*)d_in[5];
    const float* g1    = (const float*)d_in[6];
    const float* b1    = (const float*)d_in[7];
    const float* g2    = (const float*)d_in[8];
    const float* b2    = (const float*)d_in[9];
    const float* wm1   = (const float*)d_in[10];
    const float* bm1   = (const float*)d_in[11];
    const float* wm2   = (const float*)d_in[12];
    const float* bm2   = (const float*)d_in[13];
    float* outp = (float*)d_out;

    const size_t LC = (size_t)L_TOK * C_DIM;          // elements
    if (ws_size < 8 * LC) return;                     // 212.3 MB
    char* ws = (char*)d_ws;
    const size_t QB = LC * 2;                         // bytes of one bf16 L x C buffer
    unsigned short* qb  = (unsigned short*)ws;                    // [0, QB)
    unsigned short* kb  = (unsigned short*)(ws + QB);             // [QB, 2QB)
    unsigned short* vb  = (unsigned short*)(ws + 2 * QB);         // [2QB, 3QB)  (V^T layout)
    unsigned short* btT = (unsigned short*)(ws + 3 * QB);         // 37.8 MB, dead after attn
    size_t wof = 3 * QB + (size_t)WH * BIAS_ROWS * 2;
    unsigned short* wqkvT = (unsigned short*)(ws + wof);
    unsigned short* wprojT = wqkvT + (size_t)C3 * C_DIM;
    unsigned short* wm1T   = wprojT + (size_t)C_DIM * C_DIM;
    unsigned short* wm2T   = wm1T + (size_t)C_DIM * C4;
    unsigned short* aob = qb;                                     // exact per-query alias of q
    float* proj = (float*)(ws + QB);                              // over k,v (dead after attn)
    float* x1   = proj;                                           // LN1 in-place
    unsigned short* x1b = qb;                                     // over ao (dead after proj)
    unsigned short* hbuf = (unsigned short*)(ws + 3 * QB);        // over btT (dead after attn)
    float* mbuf = (float*)(ws + 3 * QB + (size_t)CHUNK * C4 * 2);

    dim3 tb(32, 8);
    k_wt<<<dim3(C3 / 32, C_DIM / 32), tb, 0, stream>>>(wqkv, wqkvT, C_DIM, C3);
    k_wt<<<dim3(C_DIM / 32, C_DIM / 32), tb, 0, stream>>>(wproj, wprojT, C_DIM, C_DIM);
    k_wt<<<dim3(C4 / 32, C_DIM / 32), tb, 0, stream>>>(wm1, wm1T, C_DIM, C4);
    k_wt<<<dim3(C_DIM / 32, C4 / 32), tb, 0, stream>>>(wm2, wm2T, C4, C_DIM);
    k_bt<<<dim3(WH / 32, (BIAS_ROWS + 31) / 32), tb, 0, stream>>>(btab, btT);

    k_qkv<<<dim3(C3 / 128, L_TOK / 128), dim3(256), 0, stream>>>(x, wqkvT, bqkv, qb, kb, vb);
    k_attn<<<dim3(WH), dim3(256), 0, stream>>>(qb, kb, vb, btT, aob);
    k_proj<<<dim3(C_DIM / 128, L_TOK / 128), dim3(256), 0, stream>>>(aob, wprojT, bproj, proj);
    k_ln_res<<<dim3(L_TOK), dim3(128), 0, stream>>>(proj, x, g1, b1, x1, x1b);
    for (int c = 0; c < NCHUNK; ++c) {
        size_t r0 = (size_t)c * CHUNK;
        k_mlp1<<<dim3(C4 / 128, CHUNK / 128), dim3(256), 0, stream>>>(x1b + r0 * C_DIM, wm1T, bm1, hbuf);
        k_mlp2<<<dim3(C_DIM / 128, CHUNK / 128), dim3(256), 0, stream>>>(hbuf, wm2T, bm2, mbuf);
        k_ln_res<<<dim3(CHUNK), dim3(128), 0, stream>>>(mbuf, x1 + r0 * C_DIM, g2, b2, outp + r0 * C_DIM, (unsigned short*)nullptr);
    }
    (void)in_sizes; (void)n_in; (void)out_size;
}